// Round 4
// baseline (22009.462 us; speedup 1.0000x reference)
//
#include <hip/hip_runtime.h>
#include <math.h>

// ---------------- problem constants ----------------
#define CB 8
#define CT 16
#define CN 256
#define CD 1280
#define CH 512
#define CS 3
#define CM (CB*CT*CN)      // 32768 rows
#define CBS (CB*CS)        // 24
#define CH3 (3*CH)         // 1536
#define CH2 (2*CH)         // 1024
#define NITER 3

// ---------------- workspace layout (float offsets) ----------------
#define OFS_P1   0ULL                       // P1, later feats (in-place): CM*CH
#define OFS_M1   16777216ULL                // M1, later k_buf (overwrite): CM*CH
#define OFS_V    33554432ULL                // vT buf: [frame][c][n]
#define OFS_ST   50331648ULL                // rowstats: CM*2
#define OFS_WQT  50397184ULL                // (unused)
#define OFS_WHHT (OFS_WQT + 262144ULL)
#define OFS_WIHT (OFS_WHHT + 786432ULL)
#define OFS_WM1T (OFS_WIHT + 786432ULL)
#define OFS_WM2T (OFS_WM1T + 524288ULL)
#define OFS_WTOT (OFS_WM2T + 524288ULL)     // 512*512 (stage 3)
#define OFS_WTQT (OFS_WTOT + 262144ULL)
#define OFS_WTKT (OFS_WTQT + 262144ULL)
#define OFS_WTVT (OFS_WTKT + 262144ULL)
#define OFS_SLOTS (OFS_WTVT + 262144ULL)    // 24*512
#define OFS_Q    (OFS_SLOTS + 12288ULL)
#define OFS_GH   (OFS_Q + 12288ULL)         // (unused)
#define OFS_ATTN (OFS_GH + 36864ULL)        // 24*256
#define OFS_U    (OFS_ATTN + 6144ULL)       // 24*512
#define OFS_Z    (OFS_U + 12288ULL)         // (unused)
#define OFS_H    (OFS_Z + 32ULL)            // 24*512
#define OFS_Y    (OFS_H + 12288ULL)         // 24*1024
#define OFS_TQKV (OFS_Y + 24576ULL)         // 384*1536
#define OFS_TO   (OFS_TQKV + 589824ULL)     // 384*512
#define OFS_BAR  (OFS_TO + 196608ULL)       // barrier counters (uints)

// ---------------- GEMM tiling ----------------
#define BM 128
#define BN 128
#define BK 8

// LDS weight slice offsets (floats), padded col stride 516 (512-col) / 1028 (1024-col)
#define WQ_OFF  0            // 2 cols
#define WHH_OFF (2*516)      // 6 cols (gate*2+cl)
#define WIH_OFF (8*516)      // 6 cols
#define WM1_OFF (14*516)     // 4 cols
#define WM2_OFF (18*516)     // 2 cols x 1028
#define WL_TOT  (18*516 + 2*1028)   // 11344 floats

// ================= init: slots0, zero agg + barrier =================
__global__ __launch_bounds__(256) void k_init(const float* __restrict__ noise,
                                              const float* __restrict__ mu,
                                              const float* __restrict__ sigma,
                                              float* __restrict__ ws,
                                              float* __restrict__ out) {
  int i = blockIdx.x * 256 + threadIdx.x;
  if (i < 12288) {
    int sj = i % 1536;  // (s,h) index into mu/sigma [1,3,512]
    ws[OFS_SLOTS + i] = mu[sj] + sigma[sj] * noise[i];
    out[i] = 0.0f;      // zero slots_agg accumulation region
  }
  if (i < 16) {
    unsigned* bar = (unsigned*)(ws + OFS_BAR);
    bar[i] = 0u;
  }
}

// ================= weight transposes (k-major) for stage-3 kernels =================
__global__ __launch_bounds__(256) void k_transpose(const float* __restrict__ w_to,
                                                   const float* __restrict__ w_tq,
                                                   const float* __restrict__ w_tk,
                                                   const float* __restrict__ w_tv,
                                                   float* __restrict__ ws) {
  const float* src; float* dst;
  switch (blockIdx.z) {
    case 0: src = w_to; dst = ws + OFS_WTOT; break;
    case 1: src = w_tq; dst = ws + OFS_WTQT; break;
    case 2: src = w_tk; dst = ws + OFS_WTKT; break;
    default: src = w_tv; dst = ws + OFS_WTVT; break;
  }
  const int R = 512, C = 512;
  int r0 = blockIdx.y * 32, c0 = blockIdx.x * 32;
  __shared__ float tile[32][33];
  int tx = threadIdx.x & 31, ty = threadIdx.x >> 5;  // 32 x 8
  for (int i = ty; i < 32; i += 8)
    tile[i][tx] = src[(size_t)(r0 + i) * C + c0 + tx];
  __syncthreads();
  for (int i = ty; i < 32; i += 8)
    dst[(size_t)(c0 + i) * R + r0 + tx] = tile[tx][i];
}

// ================= GEMM 1: P1 = visual @ w_in.T + b_in =================
__global__ __launch_bounds__(256) void k_p1(const float* __restrict__ A,
                                            const float* __restrict__ W,
                                            const float* __restrict__ bias,
                                            float* __restrict__ Cout) {
  __shared__ float As[BK][BM + 4];
  __shared__ float Bs[BK][BN + 4];
  const int tid = threadIdx.x;
  const int m0 = blockIdx.y * BM;
  const int n0 = blockIdx.x * BN;
  const int tx = tid & 15, ty = tid >> 4;
  float acc[8][8];
#pragma unroll
  for (int i = 0; i < 8; ++i)
#pragma unroll
    for (int j = 0; j < 8; ++j) acc[i][j] = 0.f;

  for (int kb = 0; kb < CD; kb += BK) {
#pragma unroll
    for (int p = 0; p < 4; ++p) {
      int r = (tid >> 3) + p * 32;
      int k = tid & 7;
      As[k][r] = A[(size_t)(m0 + r) * CD + kb + k];
      Bs[k][r] = W[(size_t)(n0 + r) * CD + kb + k];
    }
    __syncthreads();
#pragma unroll
    for (int kk = 0; kk < BK; ++kk) {
      float av[8], bv[8];
      *(float4*)&av[0] = *(const float4*)&As[kk][ty * 8];
      *(float4*)&av[4] = *(const float4*)&As[kk][ty * 8 + 4];
      *(float4*)&bv[0] = *(const float4*)&Bs[kk][tx * 8];
      *(float4*)&bv[4] = *(const float4*)&Bs[kk][tx * 8 + 4];
#pragma unroll
      for (int i = 0; i < 8; ++i)
#pragma unroll
        for (int j = 0; j < 8; ++j) acc[i][j] += av[i] * bv[j];
    }
    __syncthreads();
  }
#pragma unroll
  for (int i = 0; i < 8; ++i) {
    int m = m0 + ty * 8 + i;
#pragma unroll
    for (int j = 0; j < 8; ++j) {
      int n = n0 + tx * 8 + j;
      Cout[(size_t)m * CH + n] = acc[i][j] + bias[n];
    }
  }
}

// ================= GEMM 2: M1 = relu(motion @ w_m1p.T + b_m1p) =================
__global__ __launch_bounds__(256) void k_m1(const float* __restrict__ A,
                                            const float* __restrict__ W,
                                            const float* __restrict__ bias,
                                            float* __restrict__ Cout) {
  __shared__ float As[BK][BM + 4];
  __shared__ float Bs[BK][BN + 4];
  const int tid = threadIdx.x;
  const int m0 = blockIdx.y * BM;
  const int n0 = blockIdx.x * BN;
  const int tx = tid & 15, ty = tid >> 4;
  const int frame = (m0 >> 8);         // (b*16 + t)
  const int tfrm = frame & 15;
  float acc[8][8];
#pragma unroll
  for (int i = 0; i < 8; ++i)
#pragma unroll
    for (int j = 0; j < 8; ++j) acc[i][j] = 0.f;

  for (int kb = 0; kb < CD; kb += BK) {
#pragma unroll
    for (int p = 0; p < 4; ++p) {
      int r = (tid >> 3) + p * 32;
      int k = tid & 7;
      float mv = 0.f;
      if (tfrm < 15) {
        float cur = A[(size_t)(m0 + r) * CD + kb + k];
        float nxt = A[(size_t)(m0 + r + 256) * CD + kb + k];
        mv = nxt - cur;
      }
      As[k][r] = mv;
      Bs[k][r] = W[(size_t)(n0 + r) * CD + kb + k];
    }
    __syncthreads();
#pragma unroll
    for (int kk = 0; kk < BK; ++kk) {
      float av[8], bv[8];
      *(float4*)&av[0] = *(const float4*)&As[kk][ty * 8];
      *(float4*)&av[4] = *(const float4*)&As[kk][ty * 8 + 4];
      *(float4*)&bv[0] = *(const float4*)&Bs[kk][tx * 8];
      *(float4*)&bv[4] = *(const float4*)&Bs[kk][tx * 8 + 4];
#pragma unroll
      for (int i = 0; i < 8; ++i)
#pragma unroll
        for (int j = 0; j < 8; ++j) acc[i][j] += av[i] * bv[j];
    }
    __syncthreads();
  }
#pragma unroll
  for (int i = 0; i < 8; ++i) {
    int m = m0 + ty * 8 + i;
#pragma unroll
    for (int j = 0; j < 8; ++j) {
      int n = n0 + tx * 8 + j;
      Cout[(size_t)m * CH + n] = fmaxf(acc[i][j] + bias[n], 0.f);
    }
  }
}

// ================= row stats of P1 for LN =================
__global__ __launch_bounds__(256) void k_rowstats(const float* __restrict__ P1,
                                                  float* __restrict__ st) {
  int row = blockIdx.x * 4 + (threadIdx.x >> 6);
  int lane = threadIdx.x & 63;
  const float* r = P1 + (size_t)row * CH;
  float4 x0 = *(const float4*)&r[lane * 8];
  float4 x1 = *(const float4*)&r[lane * 8 + 4];
  float s = x0.x + x0.y + x0.z + x0.w + x1.x + x1.y + x1.z + x1.w;
  for (int o = 32; o; o >>= 1) s += __shfl_xor(s, o);
  float mean = s * (1.f / CH);
  float d, s2 = 0.f;
  d = x0.x - mean; s2 += d * d; d = x0.y - mean; s2 += d * d;
  d = x0.z - mean; s2 += d * d; d = x0.w - mean; s2 += d * d;
  d = x1.x - mean; s2 += d * d; d = x1.y - mean; s2 += d * d;
  d = x1.z - mean; s2 += d * d; d = x1.w - mean; s2 += d * d;
  for (int o = 32; o; o >>= 1) s2 += __shfl_xor(s2, o);
  if (lane == 0) {
    st[2 * row] = mean;
    st[2 * row + 1] = rsqrtf(s2 * (1.f / CH) + 1e-5f);
  }
}

// ================= GEMM 3: feats = LN(P1)*g+b + 0.5*(M1 @ w_m2p.T + b_m2p), in-place =================
__global__ __launch_bounds__(256) void k_feats(const float* __restrict__ A,  // M1
                                               const float* __restrict__ W,  // w_m2p
                                               const float* __restrict__ bias,
                                               const float* __restrict__ st,
                                               const float* __restrict__ g_ln,
                                               const float* __restrict__ b_ln,
                                               float* __restrict__ P1inout) {
  __shared__ float As[BK][BM + 4];
  __shared__ float Bs[BK][BN + 4];
  const int tid = threadIdx.x;
  const int m0 = blockIdx.y * BM;
  const int n0 = blockIdx.x * BN;
  const int tx = tid & 15, ty = tid >> 4;
  float acc[8][8];
#pragma unroll
  for (int i = 0; i < 8; ++i)
#pragma unroll
    for (int j = 0; j < 8; ++j) acc[i][j] = 0.f;

  for (int kb = 0; kb < CH; kb += BK) {
#pragma unroll
    for (int p = 0; p < 4; ++p) {
      int r = (tid >> 3) + p * 32;
      int k = tid & 7;
      As[k][r] = A[(size_t)(m0 + r) * CH + kb + k];
      Bs[k][r] = W[(size_t)(n0 + r) * CH + kb + k];
    }
    __syncthreads();
#pragma unroll
    for (int kk = 0; kk < BK; ++kk) {
      float av[8], bv[8];
      *(float4*)&av[0] = *(const float4*)&As[kk][ty * 8];
      *(float4*)&av[4] = *(const float4*)&As[kk][ty * 8 + 4];
      *(float4*)&bv[0] = *(const float4*)&Bs[kk][tx * 8];
      *(float4*)&bv[4] = *(const float4*)&Bs[kk][tx * 8 + 4];
#pragma unroll
      for (int i = 0; i < 8; ++i)
#pragma unroll
        for (int j = 0; j < 8; ++j) acc[i][j] += av[i] * bv[j];
    }
    __syncthreads();
  }
#pragma unroll
  for (int i = 0; i < 8; ++i) {
    int m = m0 + ty * 8 + i;
    float mean = st[2 * m], rstd = st[2 * m + 1];
#pragma unroll
    for (int j = 0; j < 8; ++j) {
      int n = n0 + tx * 8 + j;
      size_t idx = (size_t)m * CH + n;
      float p1v = P1inout[idx];
      float v = (p1v - mean) * rstd * g_ln[n] + b_ln[n] + 0.5f * (acc[i][j] + bias[n]);
      P1inout[idx] = v;
    }
  }
}

// ================= GEMM 4: k (row-major) | vT (transposed) = feats @ [w_k; w_v].T =================
__global__ __launch_bounds__(256) void k_kv(const float* __restrict__ A,  // feats
                                            const float* __restrict__ Wk,
                                            const float* __restrict__ Wv,
                                            float* __restrict__ kbuf,
                                            float* __restrict__ vbufT) {
  __shared__ float As[BK][BM + 4];
  __shared__ float Bs[BK][BN + 4];
  const int tid = threadIdx.x;
  const int m0 = blockIdx.y * BM;
  const int n0 = blockIdx.x * BN;  // 0..1023
  const int tx = tid & 15, ty = tid >> 4;
  const bool khalf = (n0 < 512);
  const float* W = khalf ? (Wk + (size_t)n0 * CH) : (Wv + (size_t)(n0 - 512) * CH);
  const int nbase = khalf ? n0 : (n0 - 512);
  float acc[8][8];
#pragma unroll
  for (int i = 0; i < 8; ++i)
#pragma unroll
    for (int j = 0; j < 8; ++j) acc[i][j] = 0.f;

  for (int kb = 0; kb < CH; kb += BK) {
#pragma unroll
    for (int p = 0; p < 4; ++p) {
      int r = (tid >> 3) + p * 32;
      int k = tid & 7;
      As[k][r] = A[(size_t)(m0 + r) * CH + kb + k];
      Bs[k][r] = W[(size_t)r * CH + kb + k];
    }
    __syncthreads();
#pragma unroll
    for (int kk = 0; kk < BK; ++kk) {
      float av[8], bv[8];
      *(float4*)&av[0] = *(const float4*)&As[kk][ty * 8];
      *(float4*)&av[4] = *(const float4*)&As[kk][ty * 8 + 4];
      *(float4*)&bv[0] = *(const float4*)&Bs[kk][tx * 8];
      *(float4*)&bv[4] = *(const float4*)&Bs[kk][tx * 8 + 4];
#pragma unroll
      for (int i = 0; i < 8; ++i)
#pragma unroll
        for (int j = 0; j < 8; ++j) acc[i][j] += av[i] * bv[j];
    }
    __syncthreads();
  }
#pragma unroll
  for (int i = 0; i < 8; ++i) {
    int m = m0 + ty * 8 + i;
    int frame = m >> 8, nrow = m & 255;
#pragma unroll
    for (int j = 0; j < 8; ++j) {
      int n = nbase + tx * 8 + j;
      if (khalf) kbuf[(size_t)m * CH + n] = acc[i][j];
      else       vbufT[((size_t)frame * CH + n) * CN + nrow] = acc[i][j];
    }
  }
}

// ================= device-scope grid barrier =================
__device__ inline void gbar(unsigned* bar, int nwg) {
  __threadfence();
  __syncthreads();
  if (threadIdx.x == 0) {
    unsigned g = __hip_atomic_load(&bar[1], __ATOMIC_RELAXED, __HIP_MEMORY_SCOPE_AGENT);
    unsigned a = __hip_atomic_fetch_add(&bar[0], 1u, __ATOMIC_ACQ_REL, __HIP_MEMORY_SCOPE_AGENT);
    if (a == (unsigned)(nwg - 1)) {
      __hip_atomic_store(&bar[0], 0u, __ATOMIC_RELAXED, __HIP_MEMORY_SCOPE_AGENT);
      __hip_atomic_fetch_add(&bar[1], 1u, __ATOMIC_RELEASE, __HIP_MEMORY_SCOPE_AGENT);
    } else {
      while (__hip_atomic_load(&bar[1], __ATOMIC_ACQUIRE, __HIP_MEMORY_SCOPE_AGENT) == g)
        __builtin_amdgcn_s_sleep(2);
    }
    __threadfence();
  }
  __syncthreads();
}

// ================= persistent slot-attention scan, LDS-resident weight slices =================
// 256 WGs x 512 threads. WG w owns output cols: {w*2,w*2+1} of 512-wide mats,
// {g*512 + w*2 + cl} of 1536-wide, {w*4..+4} of mlp1. Slice = 45 KB -> LDS, loaded once.
__global__ __launch_bounds__(512, 1) void k_scan(float* __restrict__ ws,
                                                 const float* __restrict__ w_q_g,
                                                 const float* __restrict__ w_hh_g,
                                                 const float* __restrict__ w_ih_g,
                                                 const float* __restrict__ w_m1_g,
                                                 const float* __restrict__ w_m2_g,
                                                 const float* __restrict__ b_ih,
                                                 const float* __restrict__ b_hh,
                                                 const float* __restrict__ g_ls,
                                                 const float* __restrict__ b_ls,
                                                 const float* __restrict__ g_lm,
                                                 const float* __restrict__ b_lm,
                                                 const float* __restrict__ b_m1,
                                                 const float* __restrict__ b_m2,
                                                 float* __restrict__ spf,
                                                 float* __restrict__ att,
                                                 int nwg) {
  const float* kbuf  = ws + OFS_M1;
  const float* vbufT = ws + OFS_V;
  float* slots = ws + OFS_SLOTS;
  float* qb    = ws + OFS_Q;
  float* attnb = ws + OFS_ATTN;
  float* Ub    = ws + OFS_U;
  float* hb    = ws + OFS_H;
  float* yb    = ws + OFS_Y;
  unsigned* bar = (unsigned*)(ws + OFS_BAR);

  __shared__ float wL[WL_TOT];
  __shared__ float partial[384];
  __shared__ float lnm[24], lnr[24];
  __shared__ float ghl[144], gg[144];
  __shared__ float izl[24];

  const int w   = blockIdx.x;      // 0..255
  const int tid = threadIdx.x;     // 0..511
  const int wv  = tid >> 6, lane = tid & 63;
  const float scale = 0.04419417382415922f;  // 512^-0.5

  // ---- preload weight slices (coalesced: original row-major rows are contiguous) ----
  for (int idx = tid; idx < 1024; idx += 512) {
    int cl = idx >> 9, k = idx & 511;
    wL[WQ_OFF + cl * 516 + k] = w_q_g[(size_t)((w << 1) + cl) * 512 + k];
  }
  for (int idx = tid; idx < 3072; idx += 512) {
    int cs = idx >> 9, k = idx & 511;
    int gate = cs >> 1, cl = cs & 1;
    wL[WHH_OFF + cs * 516 + k] = w_hh_g[(size_t)(gate * 512 + (w << 1) + cl) * 512 + k];
  }
  for (int idx = tid; idx < 3072; idx += 512) {
    int cs = idx >> 9, k = idx & 511;
    int gate = cs >> 1, cl = cs & 1;
    wL[WIH_OFF + cs * 516 + k] = w_ih_g[(size_t)(gate * 512 + (w << 1) + cl) * 512 + k];
  }
  for (int idx = tid; idx < 2048; idx += 512) {
    int cl = idx >> 9, k = idx & 511;
    wL[WM1_OFF + cl * 516 + k] = w_m1_g[(size_t)((w << 2) + cl) * 512 + k];
  }
  for (int idx = tid; idx < 2048; idx += 512) {
    int cl = idx >> 10, k = idx & 1023;
    wL[WM2_OFF + cl * 1028 + k] = w_m2_g[(size_t)((w << 1) + cl) * 1024 + k];
  }
  __syncthreads();

  for (int t = 0; t < CT; ++t) {
    for (int it = 0; it < NITER; ++it) {
      // ======== A: LN(slots) stats; gh (-> LDS ghl); q cols (-> global qb) ========
      {
        // wave wv handles rows wv*3 .. wv*3+2
        for (int rr = 0; rr < 3; ++rr) {
          int r = wv * 3 + rr;
          const float* srow = slots + r * CH;
          float4 x0 = *(const float4*)&srow[lane * 8];
          float4 x1 = *(const float4*)&srow[lane * 8 + 4];
          float s = x0.x + x0.y + x0.z + x0.w + x1.x + x1.y + x1.z + x1.w;
          for (int o = 32; o; o >>= 1) s += __shfl_xor(s, o);
          float mean = s * (1.f / CH);
          float d, s2 = 0.f;
          d = x0.x - mean; s2 += d * d; d = x0.y - mean; s2 += d * d;
          d = x0.z - mean; s2 += d * d; d = x0.w - mean; s2 += d * d;
          d = x1.x - mean; s2 += d * d; d = x1.y - mean; s2 += d * d;
          d = x1.z - mean; s2 += d * d; d = x1.w - mean; s2 += d * d;
          for (int o = 32; o; o >>= 1) s2 += __shfl_xor(s2, o);
          if (lane == 0) { lnm[r] = mean; lnr[r] = rsqrtf(s2 * (1.f / CH) + 1e-5f); }
        }
      }
      __syncthreads();
      if (tid < 384) {
        int out = tid >> 1, half = tid & 1;
        int r = out >> 3, cs = out & 7;       // cs<6: gh, cs 6/7: q
        const float* act = slots + r * CH + half * 256;
        float acc = 0.f;
        if (cs < 6) {
          const float* wl = wL + WHH_OFF + cs * 516 + half * 256;
          for (int k = 0; k < 256; k += 4) {
            float4 a = *(const float4*)&act[k];
            float4 ww = *(const float4*)&wl[k];
            acc += a.x * ww.x + a.y * ww.y + a.z * ww.z + a.w * ww.w;
          }
        } else {
          int cl = cs - 6;
          const float* wl = wL + WQ_OFF + cl * 516 + half * 256;
          float mean = lnm[r], rstd = lnr[r];
          const float* gl = g_ls + half * 256;
          const float* bl = b_ls + half * 256;
          for (int k = 0; k < 256; k += 4) {
            float4 a = *(const float4*)&act[k];
            float4 ww = *(const float4*)&wl[k];
            float4 g4 = *(const float4*)&gl[k];
            float4 b4 = *(const float4*)&bl[k];
            float x0 = (a.x - mean) * rstd * g4.x + b4.x;
            float x1 = (a.y - mean) * rstd * g4.y + b4.y;
            float x2 = (a.z - mean) * rstd * g4.z + b4.z;
            float x3 = (a.w - mean) * rstd * g4.w + b4.w;
            acc += x0 * ww.x + x1 * ww.y + x2 * ww.z + x3 * ww.w;
          }
        }
        partial[tid] = acc;
      }
      __syncthreads();
      if (tid < 192) {
        int r = tid >> 3, cs = tid & 7;
        float sum = partial[2 * tid] + partial[2 * tid + 1];
        if (cs < 6) {
          int gate = cs >> 1, cl = cs & 1;
          ghl[r * 6 + cs] = sum + b_hh[gate * 512 + (w << 1) + cl];
        } else {
          qb[r * CH + (w << 1) + (cs - 6)] = sum;
        }
      }
      gbar(bar, nwg);
      // ======== B1: logits -> softmax over s -> attn (wave per n; WG owns (b, 8 n)) ========
      {
        int b = w >> 5, n = ((w & 31) << 3) + wv;
        const float* q0 = qb + b * 3 * CH;
        const float* krow = kbuf + ((size_t)((b * CT + t) * CN + n)) * CH;
        float p0 = 0.f, p1 = 0.f, p2 = 0.f;
#pragma unroll
        for (int u = 0; u < 2; ++u) {
          int k = lane * 8 + u * 4;
          float4 kk = *(const float4*)&krow[k];
          float4 a0 = *(const float4*)&q0[k];
          float4 a1 = *(const float4*)&q0[CH + k];
          float4 a2 = *(const float4*)&q0[2 * CH + k];
          p0 += a0.x * kk.x + a0.y * kk.y + a0.z * kk.z + a0.w * kk.w;
          p1 += a1.x * kk.x + a1.y * kk.y + a1.z * kk.z + a1.w * kk.w;
          p2 += a2.x * kk.x + a2.y * kk.y + a2.z * kk.z + a2.w * kk.w;
        }
        for (int o = 32; o; o >>= 1) {
          p0 += __shfl_xor(p0, o); p1 += __shfl_xor(p1, o); p2 += __shfl_xor(p2, o);
        }
        p0 *= scale; p1 *= scale; p2 *= scale;
        float mx = fmaxf(p0, fmaxf(p1, p2));
        float e0 = expf(p0 - mx), e1 = expf(p1 - mx), e2 = expf(p2 - mx);
        float inv = 1.f / (e0 + e1 + e2);
        if (lane < 3) {
          float a = (lane == 0 ? e0 : (lane == 1 ? e1 : e2)) * inv;
          attnb[(b * 3 + lane) * CN + n] = a;
          if (it == NITER - 1)
            att[((size_t)(b * CT + t) * CS + lane) * CN + n] = a;
        }
      }
      gbar(bar, nwg);
      // ======== B2: U = (attn @ v) / Z, cols (w*2..+2) for all 24 rows ========
      {
        // Z per row (wave wv: rows wv*3..+2)
        for (int rr = 0; rr < 3; ++rr) {
          int r = wv * 3 + rr;
          float4 a = *(const float4*)&attnb[r * CN + (lane << 2)];
          float z = a.x + a.y + a.z + a.w;
          for (int o = 32; o; o >>= 1) z += __shfl_xor(z, o);
          if (lane == 0) izl[r] = 1.f / (z + 1e-8f);
        }
      }
      __syncthreads();
      if (tid < 192) {
        int out = tid >> 2, qt = tid & 3;    // out: r*2+cl
        int r = out >> 1, cl = out & 1;
        int b = r / 3;
        int c = (w << 1) + cl;
        const float* arow = attnb + r * CN + qt * 64;
        const float* vrow = vbufT + ((size_t)(b * CT + t) * CH + c) * CN + qt * 64;
        float acc = 0.f;
        for (int n = 0; n < 64; n += 4) {
          float4 a = *(const float4*)&arow[n];
          float4 v = *(const float4*)&vrow[n];
          acc += a.x * v.x + a.y * v.y + a.z * v.z + a.w * v.w;
        }
        partial[tid] = acc;
      }
      __syncthreads();
      if (tid < 48) {
        int r = tid >> 1, cl = tid & 1;
        float u = (partial[4 * tid] + partial[4 * tid + 1] + partial[4 * tid + 2] + partial[4 * tid + 3]) * izl[r];
        Ub[r * CH + (w << 1) + cl] = u;
      }
      gbar(bar, nwg);
      // ======== C: gi = U @ w_ih.T + b_ih (6 cols); GRU combine -> h cols ========
      if (tid < 288) {
        int out = tid >> 1, half = tid & 1;
        int r = out / 6, cs = out % 6;
        const float* act = Ub + r * CH + half * 256;
        const float* wl = wL + WIH_OFF + cs * 516 + half * 256;
        float acc = 0.f;
        for (int k = 0; k < 256; k += 4) {
          float4 a = *(const float4*)&act[k];
          float4 ww = *(const float4*)&wl[k];
          acc += a.x * ww.x + a.y * ww.y + a.z * ww.z + a.w * ww.w;
        }
        partial[tid] = acc;
      }
      __syncthreads();
      if (tid < 144) {
        int r = tid / 6, cs = tid % 6;
        int gate = cs >> 1, cl = cs & 1;
        gg[r * 6 + cs] = partial[2 * tid] + partial[2 * tid + 1] + b_ih[gate * 512 + (w << 1) + cl];
      }
      __syncthreads();
      if (tid < 48) {
        int r = tid >> 1, cl = tid & 1;
        int j = (w << 1) + cl;
        float ir = gg[r * 6 + cl],     iz = gg[r * 6 + 2 + cl],  inn = gg[r * 6 + 4 + cl];
        float hr = ghl[r * 6 + cl],    hz = ghl[r * 6 + 2 + cl], hn  = ghl[r * 6 + 4 + cl];
        float rr = 1.f / (1.f + expf(-(ir + hr)));
        float zz = 1.f / (1.f + expf(-(iz + hz)));
        float nn = tanhf(inn + rr * hn);
        hb[r * CH + j] = (1.f - zz) * nn + zz * slots[r * CH + j];
      }
      gbar(bar, nwg);
      // ======== D: y = gelu(LN(h) @ w_mlp1.T + b_m1), 4 cols ========
      {
        for (int rr = 0; rr < 3; ++rr) {
          int r = wv * 3 + rr;
          const float* hrow = hb + r * CH;
          float4 x0 = *(const float4*)&hrow[lane * 8];
          float4 x1 = *(const float4*)&hrow[lane * 8 + 4];
          float s = x0.x + x0.y + x0.z + x0.w + x1.x + x1.y + x1.z + x1.w;
          for (int o = 32; o; o >>= 1) s += __shfl_xor(s, o);
          float mean = s * (1.f / CH);
          float d, s2 = 0.f;
          d = x0.x - mean; s2 += d * d; d = x0.y - mean; s2 += d * d;
          d = x0.z - mean; s2 += d * d; d = x0.w - mean; s2 += d * d;
          d = x1.x - mean; s2 += d * d; d = x1.y - mean; s2 += d * d;
          d = x1.z - mean; s2 += d * d; d = x1.w - mean; s2 += d * d;
          for (int o = 32; o; o >>= 1) s2 += __shfl_xor(s2, o);
          if (lane == 0) { lnm[r] = mean; lnr[r] = rsqrtf(s2 * (1.f / CH) + 1e-5f); }
        }
      }
      __syncthreads();
      if (tid < 192) {
        int out = tid >> 1, half = tid & 1;
        int r = out >> 2, cl = out & 3;
        const float* act = hb + r * CH + half * 256;
        const float* wl = wL + WM1_OFF + cl * 516 + half * 256;
        float mean = lnm[r], rstd = lnr[r];
        const float* gl = g_lm + half * 256;
        const float* bl = b_lm + half * 256;
        float acc = 0.f;
        for (int k = 0; k < 256; k += 4) {
          float4 a = *(const float4*)&act[k];
          float4 ww = *(const float4*)&wl[k];
          float4 g4 = *(const float4*)&gl[k];
          float4 b4 = *(const float4*)&bl[k];
          float x0 = (a.x - mean) * rstd * g4.x + b4.x;
          float x1 = (a.y - mean) * rstd * g4.y + b4.y;
          float x2 = (a.z - mean) * rstd * g4.z + b4.z;
          float x3 = (a.w - mean) * rstd * g4.w + b4.w;
          acc += x0 * ww.x + x1 * ww.y + x2 * ww.z + x3 * ww.w;
        }
        partial[tid] = acc;
      }
      __syncthreads();
      if (tid < 96) {
        int r = tid >> 2, cl = tid & 3;
        int c = (w << 2) + cl;
        float acc = partial[2 * tid] + partial[2 * tid + 1] + b_m1[c];
        float g = 0.5f * acc * (1.f + erff(acc * 0.70710678118654752f));
        yb[r * CH2 + c] = g;
      }
      gbar(bar, nwg);
      // ======== E: slots' = h + y @ w_mlp2.T + b_m2, 2 cols ========
      if (tid < 192) {
        int out = tid >> 2, qt = tid & 3;
        int r = out >> 1, cl = out & 1;
        const float* act = yb + r * CH2 + qt * 256;
        const float* wl = wL + WM2_OFF + cl * 1028 + qt * 256;
        float acc = 0.f;
        for (int k = 0; k < 256; k += 4) {
          float4 a = *(const float4*)&act[k];
          float4 ww = *(const float4*)&wl[k];
          acc += a.x * ww.x + a.y * ww.y + a.z * ww.z + a.w * ww.w;
        }
        partial[tid] = acc;
      }
      __syncthreads();
      if (tid < 48) {
        int r = tid >> 1, cl = tid & 1;
        int j = (w << 1) + cl;
        float sn = hb[r * CH + j] + partial[4 * tid] + partial[4 * tid + 1] +
                   partial[4 * tid + 2] + partial[4 * tid + 3] + b_m2[j];
        slots[r * CH + j] = sn;
        if (it == NITER - 1) {
          int b = r / 3, s5 = r % 3;
          spf[((size_t)(b * CT + t) * CS + s5) * CH + j] = sn;
        }
      }
      gbar(bar, nwg);
    }
  }
}

// ================= temporal attention: qkv projection =================
__global__ __launch_bounds__(256) void k_tproj(const float* __restrict__ spf,
                                               const float* __restrict__ ws_c,
                                               const float* __restrict__ b_tq,
                                               const float* __restrict__ b_tk,
                                               const float* __restrict__ b_tv,
                                               float* __restrict__ tqkv) {
  __shared__ float xr[CH];
  int row = blockIdx.x;  // bs*16 + t
  int bs = row >> 4, t = row & 15;
  int b = bs / 3, s = bs % 3;
  const float* x = spf + ((size_t)(b * CT + t) * CS + s) * CH;
  for (int i = threadIdx.x; i < CH; i += 256) xr[i] = x[i];
  __syncthreads();
  for (int p = 0; p < 6; ++p) {
    int j = p * 256 + threadIdx.x;
    const float* wT; const float* bb; int jj;
    if (j < 512)      { wT = ws_c + OFS_WTQT; bb = b_tq; jj = j; }
    else if (j < 1024){ wT = ws_c + OFS_WTKT; bb = b_tk; jj = j - 512; }
    else              { wT = ws_c + OFS_WTVT; bb = b_tv; jj = j - 1024; }
    float acc = bb[jj];
    for (int h = 0; h < CH; ++h) acc += xr[h] * wT[h * CH + jj];
    tqkv[(size_t)row * CH3 + j] = acc;
  }
}

// ================= temporal attention: per (track, head) =================
__global__ __launch_bounds__(64) void k_tattn(const float* __restrict__ tqkv,
                                              float* __restrict__ ob) {
  __shared__ float qs[16][68], ks[16][68], vs[16][68], sc[16][20];
  int bs = blockIdx.x >> 3, hh = blockIdx.x & 7;
  int lane = threadIdx.x;
  for (int i = 0; i < 16; ++i) {
    const float* base = tqkv + (size_t)(bs * 16 + i) * CH3 + hh * 64;
    qs[i][lane] = base[lane];
    ks[i][lane] = base[512 + lane];
    vs[i][lane] = base[1024 + lane];
  }
  __syncthreads();
  for (int u = 0; u < 4; ++u) {
    int ee = u * 64 + lane;
    int i = ee >> 4, j = ee & 15;
    float acc = 0.f;
    for (int d = 0; d < 64; ++d) acc += qs[i][d] * ks[j][d];
    sc[i][j] = acc * 0.125f;  // 1/sqrt(64)
  }
  __syncthreads();
  if (lane < 16) {
    float mx = -1e30f;
    for (int j = 0; j < 16; ++j) mx = fmaxf(mx, sc[lane][j]);
    float sum = 0.f;
    for (int j = 0; j < 16; ++j) { float ev = expf(sc[lane][j] - mx); sc[lane][j] = ev; sum += ev; }
    float inv = 1.f / sum;
    for (int j = 0; j < 16; ++j) sc[lane][j] *= inv;
  }
  __syncthreads();
  for (int i = 0; i < 16; ++i) {
    float acc = 0.f;
    for (int j = 0; j < 16; ++j) acc += sc[i][j] * vs[j][lane];
    ob[(size_t)(bs * 16 + i) * CH + hh * 64 + lane] = acc;
  }
}

// ================= temporal out-proj + residual + LN + mean =================
__global__ __launch_bounds__(256) void k_tout(const float* __restrict__ ob,
                                              const float* __restrict__ spf,
                                              const float* __restrict__ ws_c,
                                              const float* __restrict__ b_to,
                                              const float* __restrict__ g_lt,
                                              const float* __restrict__ b_lt,
                                              float* __restrict__ agg) {
  __shared__ float orow[CH], rrow[CH], red[8];
  int row = blockIdx.x;
  int bs = row >> 4, t = row & 15;
  int b = bs / 3, s = bs % 3;
  const float* x = spf + ((size_t)(b * CT + t) * CS + s) * CH;
  const float* o = ob + (size_t)row * CH;
  for (int i = threadIdx.x; i < CH; i += 256) orow[i] = o[i];
  __syncthreads();
  const float* wto = ws_c + OFS_WTOT;
  for (int p = 0; p < 2; ++p) {
    int j = p * 256 + threadIdx.x;
    float acc = b_to[j];
    for (int c = 0; c < CH; ++c) acc += orow[c] * wto[c * CH + j];
    rrow[j] = acc + x[j];
  }
  __syncthreads();
  float part = rrow[threadIdx.x] + rrow[threadIdx.x + 256];
  for (int o2 = 32; o2; o2 >>= 1) part += __shfl_xor(part, o2);
  if ((threadIdx.x & 63) == 0) red[threadIdx.x >> 6] = part;
  __syncthreads();
  float mean = (red[0] + red[1] + red[2] + red[3]) * (1.f / CH);
  float d0 = rrow[threadIdx.x] - mean, d1 = rrow[threadIdx.x + 256] - mean;
  float p2 = d0 * d0 + d1 * d1;
  for (int o2 = 32; o2; o2 >>= 1) p2 += __shfl_xor(p2, o2);
  __syncthreads();
  if ((threadIdx.x & 63) == 0) red[(threadIdx.x >> 6) + 4] = p2;
  __syncthreads();
  float rstd = rsqrtf((red[4] + red[5] + red[6] + red[7]) * (1.f / CH) + 1e-5f);
  for (int p = 0; p < 2; ++p) {
    int j = p * 256 + threadIdx.x;
    float xt = (rrow[j] - mean) * rstd * g_lt[j] + b_lt[j];
    atomicAdd(&agg[(size_t)bs * CH + j], xt * (1.f / CT));
  }
}

// ================= launch =================
extern "C" void kernel_launch(void* const* d_in, const int* in_sizes, int n_in,
                              void* d_out, int out_size, void* d_ws, size_t ws_size,
                              hipStream_t stream) {
  (void)in_sizes; (void)n_in; (void)out_size; (void)ws_size;
  const float* visual = (const float*)d_in[0];
  const float* noise  = (const float*)d_in[1];
  const float* mu     = (const float*)d_in[2];
  const float* sigma  = (const float*)d_in[3];
  const float* w_in   = (const float*)d_in[4];
  const float* b_in   = (const float*)d_in[5];
  const float* g_lin  = (const float*)d_in[6];
  const float* b_lin  = (const float*)d_in[7];
  const float* w_m1p  = (const float*)d_in[8];
  const float* b_m1p  = (const float*)d_in[9];
  const float* w_m2p  = (const float*)d_in[10];
  const float* b_m2p  = (const float*)d_in[11];
  const float* w_q    = (const float*)d_in[12];
  const float* w_k    = (const float*)d_in[13];
  const float* w_v    = (const float*)d_in[14];
  const float* w_ih   = (const float*)d_in[15];
  const float* w_hh   = (const float*)d_in[16];
  const float* b_ih   = (const float*)d_in[17];
  const float* b_hh   = (const float*)d_in[18];
  const float* g_ls   = (const float*)d_in[19];
  const float* b_ls   = (const float*)d_in[20];
  const float* g_lm   = (const float*)d_in[21];
  const float* b_lm   = (const float*)d_in[22];
  const float* w_mlp1 = (const float*)d_in[23];
  const float* b_mlp1 = (const float*)d_in[24];
  const float* w_mlp2 = (const float*)d_in[25];
  const float* b_mlp2 = (const float*)d_in[26];
  const float* w_tq   = (const float*)d_in[27];
  const float* b_tq   = (const float*)d_in[28];
  const float* w_tk   = (const float*)d_in[29];
  const float* b_tk   = (const float*)d_in[30];
  const float* w_tv   = (const float*)d_in[31];
  const float* b_tv   = (const float*)d_in[32];
  const float* w_to   = (const float*)d_in[33];
  const float* b_to   = (const float*)d_in[34];
  const float* g_lt   = (const float*)d_in[35];
  const float* b_lt   = (const float*)d_in[36];

  float* ws  = (float*)d_ws;
  float* out = (float*)d_out;
  float* spf = out + 12288;
  float* att = out + 12288 + 196608;

  hipLaunchKernelGGL(k_init, dim3(48), dim3(256), 0, stream, noise, mu, sigma, ws, out);
  hipLaunchKernelGGL(k_transpose, dim3(16, 16, 4), dim3(256), 0, stream,
                     w_to, w_tq, w_tk, w_tv, ws);
  // Stage 1
  hipLaunchKernelGGL(k_p1, dim3(4, 256), dim3(256), 0, stream,
                     visual, w_in, b_in, ws + OFS_P1);
  hipLaunchKernelGGL(k_rowstats, dim3(CM / 4), dim3(256), 0, stream,
                     ws + OFS_P1, ws + OFS_ST);
  hipLaunchKernelGGL(k_m1, dim3(4, 256), dim3(256), 0, stream,
                     visual, w_m1p, b_m1p, ws + OFS_M1);
  hipLaunchKernelGGL(k_feats, dim3(4, 256), dim3(256), 0, stream,
                     ws + OFS_M1, w_m2p, b_m2p, ws + OFS_ST, g_lin, b_lin, ws + OFS_P1);
  hipLaunchKernelGGL(k_kv, dim3(8, 256), dim3(256), 0, stream,
                     ws + OFS_P1, w_k, w_v, ws + OFS_M1, ws + OFS_V);
  // Stage 2: persistent scan (256 WGs x 512 thr, LDS-resident weight slices)
  hipLaunchKernelGGL(k_scan, dim3(256), dim3(512), 0, stream,
                     ws, w_q, w_hh, w_ih, w_mlp1, w_mlp2,
                     b_ih, b_hh, g_ls, b_ls, g_lm, b_lm, b_mlp1, b_mlp2,
                     spf, att, 256);
  // Stage 3: temporal attention
  hipLaunchKernelGGL(k_tproj, dim3(384), dim3(256), 0, stream,
                     spf, ws, b_tq, b_tk, b_tv, ws + OFS_TQKV);
  hipLaunchKernelGGL(k_tattn, dim3(192), dim3(64), 0, stream,
                     ws + OFS_TQKV, ws + OFS_TO);
  hipLaunchKernelGGL(k_tout, dim3(384), dim3(256), 0, stream,
                     ws + OFS_TO, spf, ws, b_to, g_lt, b_lt, out);
}

// Round 6
// 7999.615 us; speedup vs baseline: 2.7513x; 2.7513x over previous
//
#include <hip/hip_runtime.h>
#include <math.h>

// ---------------- problem constants ----------------
#define CB 8
#define CT 16
#define CN 256
#define CD 1280
#define CH 512
#define CS 3
#define CM (CB*CT*CN)      // 32768 rows
#define CBS (CB*CS)        // 24
#define CH3 (3*CH)         // 1536
#define CH2 (2*CH)         // 1024
#define NITER 3

// ---------------- workspace layout (float offsets) ----------------
#define OFS_P1   0ULL                       // P1, later feats (in-place): CM*CH
#define OFS_M1   16777216ULL                // M1, later k_buf (overwrite): CM*CH
#define OFS_V    33554432ULL                // v buf (row-major): CM*CH
#define OFS_ST   50331648ULL                // rowstats: CM*2
#define OFS_WQT  50397184ULL                // wqT  [k=512][512]
#define OFS_WHHT (OFS_WQT + 262144ULL)      // whhT [k=512][1536]
#define OFS_WIHT (OFS_WHHT + 786432ULL)     // wihT [k=512][1536]
#define OFS_WM1T (OFS_WIHT + 786432ULL)     // wm1T [k=512][1024]
#define OFS_WM2T (OFS_WM1T + 524288ULL)     // wm2T [k=1024][512]
#define OFS_WTOT (OFS_WM2T + 524288ULL)     // stage-3 transposes
#define OFS_WTQT (OFS_WTOT + 262144ULL)
#define OFS_WTKT (OFS_WTQT + 262144ULL)
#define OFS_WTVT (OFS_WTKT + 262144ULL)
#define OFS_SLOTS (OFS_WTVT + 262144ULL)    // 24*512
#define OFS_Q    (OFS_SLOTS + 12288ULL)     // 24*512
#define OFS_GH   (OFS_Q + 12288ULL)         // 24*1536
#define OFS_ATTN (OFS_GH + 36864ULL)        // 24*256
#define OFS_U    (OFS_ATTN + 6144ULL)       // 24*512
#define OFS_Z    (OFS_U + 12288ULL)         // (unused)
#define OFS_H    (OFS_Z + 32ULL)            // 24*512
#define OFS_Y    (OFS_H + 12288ULL)         // 24*1024
#define OFS_TQKV (OFS_Y + 24576ULL)         // 384*1536
#define OFS_TO   (OFS_TQKV + 589824ULL)     // 384*512

// ---------------- GEMM tiling ----------------
#define BM 128
#define BN 128
#define BK 8

// ================= init: slots0, zero agg =================
__global__ __launch_bounds__(256) void k_init(const float* __restrict__ noise,
                                              const float* __restrict__ mu,
                                              const float* __restrict__ sigma,
                                              float* __restrict__ ws,
                                              float* __restrict__ out) {
  int i = blockIdx.x * 256 + threadIdx.x;
  if (i < 12288) {
    int sj = i % 1536;  // (s,h) index into mu/sigma [1,3,512]
    ws[OFS_SLOTS + i] = mu[sj] + sigma[sj] * noise[i];
    out[i] = 0.0f;      // zero slots_agg accumulation region
  }
}

// ================= weight transposes (k-major) =================
__global__ __launch_bounds__(256) void k_transpose(const float* __restrict__ w_q,
                                                   const float* __restrict__ w_hh,
                                                   const float* __restrict__ w_ih,
                                                   const float* __restrict__ w_mlp1,
                                                   const float* __restrict__ w_mlp2,
                                                   const float* __restrict__ w_to,
                                                   const float* __restrict__ w_tq,
                                                   const float* __restrict__ w_tk,
                                                   const float* __restrict__ w_tv,
                                                   float* __restrict__ ws) {
  const float* src; float* dst; int R, C;
  switch (blockIdx.z) {
    case 0: src = w_q;    dst = ws + OFS_WQT;  R = 512;  C = 512;  break;
    case 1: src = w_hh;   dst = ws + OFS_WHHT; R = 1536; C = 512;  break;
    case 2: src = w_ih;   dst = ws + OFS_WIHT; R = 1536; C = 512;  break;
    case 3: src = w_mlp1; dst = ws + OFS_WM1T; R = 1024; C = 512;  break;
    case 4: src = w_mlp2; dst = ws + OFS_WM2T; R = 512;  C = 1024; break;
    case 5: src = w_to;   dst = ws + OFS_WTOT; R = 512;  C = 512;  break;
    case 6: src = w_tq;   dst = ws + OFS_WTQT; R = 512;  C = 512;  break;
    case 7: src = w_tk;   dst = ws + OFS_WTKT; R = 512;  C = 512;  break;
    default: src = w_tv;  dst = ws + OFS_WTVT; R = 512;  C = 512;  break;
  }
  int r0 = blockIdx.y * 32, c0 = blockIdx.x * 32;
  if (r0 >= R || c0 >= C) return;
  __shared__ float tile[32][33];
  int tx = threadIdx.x & 31, ty = threadIdx.x >> 5;  // 32 x 8
  for (int i = ty; i < 32; i += 8)
    tile[i][tx] = src[(size_t)(r0 + i) * C + c0 + tx];
  __syncthreads();
  // dst[c*R + r] = src[r*C + c]  -> dst is [in_dim k][out_col]
  for (int i = ty; i < 32; i += 8)
    dst[(size_t)(c0 + i) * R + r0 + tx] = tile[tx][i];
}

// ================= GEMM 1: P1 = visual @ w_in.T + b_in =================
__global__ __launch_bounds__(256) void k_p1(const float* __restrict__ A,
                                            const float* __restrict__ W,
                                            const float* __restrict__ bias,
                                            float* __restrict__ Cout) {
  __shared__ float As[BK][BM + 4];
  __shared__ float Bs[BK][BN + 4];
  const int tid = threadIdx.x;
  const int m0 = blockIdx.y * BM;
  const int n0 = blockIdx.x * BN;
  const int tx = tid & 15, ty = tid >> 4;
  float acc[8][8];
#pragma unroll
  for (int i = 0; i < 8; ++i)
#pragma unroll
    for (int j = 0; j < 8; ++j) acc[i][j] = 0.f;

  for (int kb = 0; kb < CD; kb += BK) {
#pragma unroll
    for (int p = 0; p < 4; ++p) {
      int r = (tid >> 3) + p * 32;
      int k = tid & 7;
      As[k][r] = A[(size_t)(m0 + r) * CD + kb + k];
      Bs[k][r] = W[(size_t)(n0 + r) * CD + kb + k];
    }
    __syncthreads();
#pragma unroll
    for (int kk = 0; kk < BK; ++kk) {
      float av[8], bv[8];
      *(float4*)&av[0] = *(const float4*)&As[kk][ty * 8];
      *(float4*)&av[4] = *(const float4*)&As[kk][ty * 8 + 4];
      *(float4*)&bv[0] = *(const float4*)&Bs[kk][tx * 8];
      *(float4*)&bv[4] = *(const float4*)&Bs[kk][tx * 8 + 4];
#pragma unroll
      for (int i = 0; i < 8; ++i)
#pragma unroll
        for (int j = 0; j < 8; ++j) acc[i][j] += av[i] * bv[j];
    }
    __syncthreads();
  }
#pragma unroll
  for (int i = 0; i < 8; ++i) {
    int m = m0 + ty * 8 + i;
#pragma unroll
    for (int j = 0; j < 8; ++j) {
      int n = n0 + tx * 8 + j;
      Cout[(size_t)m * CH + n] = acc[i][j] + bias[n];
    }
  }
}

// ================= GEMM 2: M1 = relu(motion @ w_m1p.T + b_m1p) =================
__global__ __launch_bounds__(256) void k_m1(const float* __restrict__ A,
                                            const float* __restrict__ W,
                                            const float* __restrict__ bias,
                                            float* __restrict__ Cout) {
  __shared__ float As[BK][BM + 4];
  __shared__ float Bs[BK][BN + 4];
  const int tid = threadIdx.x;
  const int m0 = blockIdx.y * BM;
  const int n0 = blockIdx.x * BN;
  const int tx = tid & 15, ty = tid >> 4;
  const int frame = (m0 >> 8);         // (b*16 + t)
  const int tfrm = frame & 15;
  float acc[8][8];
#pragma unroll
  for (int i = 0; i < 8; ++i)
#pragma unroll
    for (int j = 0; j < 8; ++j) acc[i][j] = 0.f;

  for (int kb = 0; kb < CD; kb += BK) {
#pragma unroll
    for (int p = 0; p < 4; ++p) {
      int r = (tid >> 3) + p * 32;
      int k = tid & 7;
      float mv = 0.f;
      if (tfrm < 15) {
        float cur = A[(size_t)(m0 + r) * CD + kb + k];
        float nxt = A[(size_t)(m0 + r + 256) * CD + kb + k];
        mv = nxt - cur;
      }
      As[k][r] = mv;
      Bs[k][r] = W[(size_t)(n0 + r) * CD + kb + k];
    }
    __syncthreads();
#pragma unroll
    for (int kk = 0; kk < BK; ++kk) {
      float av[8], bv[8];
      *(float4*)&av[0] = *(const float4*)&As[kk][ty * 8];
      *(float4*)&av[4] = *(const float4*)&As[kk][ty * 8 + 4];
      *(float4*)&bv[0] = *(const float4*)&Bs[kk][tx * 8];
      *(float4*)&bv[4] = *(const float4*)&Bs[kk][tx * 8 + 4];
#pragma unroll
      for (int i = 0; i < 8; ++i)
#pragma unroll
        for (int j = 0; j < 8; ++j) acc[i][j] += av[i] * bv[j];
    }
    __syncthreads();
  }
#pragma unroll
  for (int i = 0; i < 8; ++i) {
    int m = m0 + ty * 8 + i;
#pragma unroll
    for (int j = 0; j < 8; ++j) {
      int n = n0 + tx * 8 + j;
      Cout[(size_t)m * CH + n] = fmaxf(acc[i][j] + bias[n], 0.f);
    }
  }
}

// ================= row stats of P1 for LN =================
__global__ __launch_bounds__(256) void k_rowstats(const float* __restrict__ P1,
                                                  float* __restrict__ st) {
  int row = blockIdx.x * 4 + (threadIdx.x >> 6);
  int lane = threadIdx.x & 63;
  const float* r = P1 + (size_t)row * CH;
  float4 x0 = *(const float4*)&r[lane * 8];
  float4 x1 = *(const float4*)&r[lane * 8 + 4];
  float s = x0.x + x0.y + x0.z + x0.w + x1.x + x1.y + x1.z + x1.w;
  for (int o = 32; o; o >>= 1) s += __shfl_xor(s, o);
  float mean = s * (1.f / CH);
  float d, s2 = 0.f;
  d = x0.x - mean; s2 += d * d; d = x0.y - mean; s2 += d * d;
  d = x0.z - mean; s2 += d * d; d = x0.w - mean; s2 += d * d;
  d = x1.x - mean; s2 += d * d; d = x1.y - mean; s2 += d * d;
  d = x1.z - mean; s2 += d * d; d = x1.w - mean; s2 += d * d;
  for (int o = 32; o; o >>= 1) s2 += __shfl_xor(s2, o);
  if (lane == 0) {
    st[2 * row] = mean;
    st[2 * row + 1] = rsqrtf(s2 * (1.f / CH) + 1e-5f);
  }
}

// ================= GEMM 3: feats = LN(P1)*g+b + 0.5*(M1 @ w_m2p.T + b_m2p), in-place =================
__global__ __launch_bounds__(256) void k_feats(const float* __restrict__ A,  // M1
                                               const float* __restrict__ W,  // w_m2p
                                               const float* __restrict__ bias,
                                               const float* __restrict__ st,
                                               const float* __restrict__ g_ln,
                                               const float* __restrict__ b_ln,
                                               float* __restrict__ P1inout) {
  __shared__ float As[BK][BM + 4];
  __shared__ float Bs[BK][BN + 4];
  const int tid = threadIdx.x;
  const int m0 = blockIdx.y * BM;
  const int n0 = blockIdx.x * BN;
  const int tx = tid & 15, ty = tid >> 4;
  float acc[8][8];
#pragma unroll
  for (int i = 0; i < 8; ++i)
#pragma unroll
    for (int j = 0; j < 8; ++j) acc[i][j] = 0.f;

  for (int kb = 0; kb < CH; kb += BK) {
#pragma unroll
    for (int p = 0; p < 4; ++p) {
      int r = (tid >> 3) + p * 32;
      int k = tid & 7;
      As[k][r] = A[(size_t)(m0 + r) * CH + kb + k];
      Bs[k][r] = W[(size_t)(n0 + r) * CH + kb + k];
    }
    __syncthreads();
#pragma unroll
    for (int kk = 0; kk < BK; ++kk) {
      float av[8], bv[8];
      *(float4*)&av[0] = *(const float4*)&As[kk][ty * 8];
      *(float4*)&av[4] = *(const float4*)&As[kk][ty * 8 + 4];
      *(float4*)&bv[0] = *(const float4*)&Bs[kk][tx * 8];
      *(float4*)&bv[4] = *(const float4*)&Bs[kk][tx * 8 + 4];
#pragma unroll
      for (int i = 0; i < 8; ++i)
#pragma unroll
        for (int j = 0; j < 8; ++j) acc[i][j] += av[i] * bv[j];
    }
    __syncthreads();
  }
#pragma unroll
  for (int i = 0; i < 8; ++i) {
    int m = m0 + ty * 8 + i;
    float mean = st[2 * m], rstd = st[2 * m + 1];
#pragma unroll
    for (int j = 0; j < 8; ++j) {
      int n = n0 + tx * 8 + j;
      size_t idx = (size_t)m * CH + n;
      float p1v = P1inout[idx];
      float v = (p1v - mean) * rstd * g_ln[n] + b_ln[n] + 0.5f * (acc[i][j] + bias[n]);
      P1inout[idx] = v;
    }
  }
}

// ================= GEMM 4: k | v (both row-major) = feats @ [w_k; w_v].T =================
__global__ __launch_bounds__(256) void k_kv(const float* __restrict__ A,  // feats
                                            const float* __restrict__ Wk,
                                            const float* __restrict__ Wv,
                                            float* __restrict__ kbuf,
                                            float* __restrict__ vbuf) {
  __shared__ float As[BK][BM + 4];
  __shared__ float Bs[BK][BN + 4];
  const int tid = threadIdx.x;
  const int m0 = blockIdx.y * BM;
  const int n0 = blockIdx.x * BN;  // 0..1023
  const int tx = tid & 15, ty = tid >> 4;
  const bool khalf = (n0 < 512);
  const float* W = khalf ? (Wk + (size_t)n0 * CH) : (Wv + (size_t)(n0 - 512) * CH);
  float* Out = khalf ? kbuf : vbuf;
  const int nbase = khalf ? n0 : (n0 - 512);
  float acc[8][8];
#pragma unroll
  for (int i = 0; i < 8; ++i)
#pragma unroll
    for (int j = 0; j < 8; ++j) acc[i][j] = 0.f;

  for (int kb = 0; kb < CH; kb += BK) {
#pragma unroll
    for (int p = 0; p < 4; ++p) {
      int r = (tid >> 3) + p * 32;
      int k = tid & 7;
      As[k][r] = A[(size_t)(m0 + r) * CH + kb + k];
      Bs[k][r] = W[(size_t)r * CH + kb + k];
    }
    __syncthreads();
#pragma unroll
    for (int kk = 0; kk < BK; ++kk) {
      float av[8], bv[8];
      *(float4*)&av[0] = *(const float4*)&As[kk][ty * 8];
      *(float4*)&av[4] = *(const float4*)&As[kk][ty * 8 + 4];
      *(float4*)&bv[0] = *(const float4*)&Bs[kk][tx * 8];
      *(float4*)&bv[4] = *(const float4*)&Bs[kk][tx * 8 + 4];
#pragma unroll
      for (int i = 0; i < 8; ++i)
#pragma unroll
        for (int j = 0; j < 8; ++j) acc[i][j] += av[i] * bv[j];
    }
    __syncthreads();
  }
#pragma unroll
  for (int i = 0; i < 8; ++i) {
    int m = m0 + ty * 8 + i;
#pragma unroll
    for (int j = 0; j < 8; ++j) {
      int n = nbase + tx * 8 + j;
      Out[(size_t)m * CH + n] = acc[i][j];
    }
  }
}

// ============================================================================
// Slot-attention scan, phase-split: 6 tiny kernels per (t,it). Kernel-launch
// boundaries replace the device barrier (round-4 post-mortem: 256-WG atomic
// barrier was ~60µs each; graph nodes are ~2-3µs).
// ============================================================================

// ---- Phase A: LN(slots) -> q (cols) ; slots -> gh (cols). grid (8, 24) ----
__global__ __launch_bounds__(256) void ph_A(float* __restrict__ ws,
                                            const float* __restrict__ g_ls,
                                            const float* __restrict__ b_ls,
                                            const float* __restrict__ b_hh) {
  const int r = blockIdx.y;        // 0..23
  const int chunk = blockIdx.x;    // 0..7 over 2048 concatenated [q|gh] cols
  const int tid = threadIdx.x;
  const float* srow = ws + OFS_SLOTS + (size_t)r * CH;
  __shared__ float sraw[CH], sln[CH], red[8];
  float v0 = srow[tid], v1 = srow[tid + 256];
  sraw[tid] = v0; sraw[tid + 256] = v1;
  float s = v0 + v1;
  for (int o = 32; o; o >>= 1) s += __shfl_xor(s, o);
  if ((tid & 63) == 0) red[tid >> 6] = s;
  __syncthreads();
  float mean = (red[0] + red[1] + red[2] + red[3]) * (1.f / CH);
  float d0 = v0 - mean, d1 = v1 - mean;
  float s2 = d0 * d0 + d1 * d1;
  for (int o = 32; o; o >>= 1) s2 += __shfl_xor(s2, o);
  if ((tid & 63) == 0) red[(tid >> 6) + 4] = s2;
  __syncthreads();
  float rstd = rsqrtf((red[4] + red[5] + red[6] + red[7]) * (1.f / CH) + 1e-5f);
  sln[tid]       = d0 * rstd * g_ls[tid] + b_ls[tid];
  sln[tid + 256] = d1 * rstd * g_ls[tid + 256] + b_ls[tid + 256];
  __syncthreads();
  int c = chunk * 256 + tid;
  if (c < CH) {                                   // q column (chunks 0,1)
    const float* w = ws + OFS_WQT + c;            // wqT [k][512]
    float a0 = 0.f, a1 = 0.f, a2 = 0.f, a3 = 0.f;
    for (int k = 0; k < CH; k += 4) {
      a0 += sln[k]     * w[(size_t)(k)     * CH];
      a1 += sln[k + 1] * w[(size_t)(k + 1) * CH];
      a2 += sln[k + 2] * w[(size_t)(k + 2) * CH];
      a3 += sln[k + 3] * w[(size_t)(k + 3) * CH];
    }
    ws[OFS_Q + (size_t)r * CH + c] = a0 + a1 + a2 + a3;
  } else {                                        // gh column (chunks 2..7)
    int cg = c - CH;                              // 0..1535
    const float* w = ws + OFS_WHHT + cg;          // whhT [k][1536]
    float a0 = 0.f, a1 = 0.f, a2 = 0.f, a3 = 0.f;
    for (int k = 0; k < CH; k += 4) {
      a0 += sraw[k]     * w[(size_t)(k)     * CH3];
      a1 += sraw[k + 1] * w[(size_t)(k + 1) * CH3];
      a2 += sraw[k + 2] * w[(size_t)(k + 2) * CH3];
      a3 += sraw[k + 3] * w[(size_t)(k + 3) * CH3];
    }
    ws[OFS_GH + (size_t)r * CH3 + cg] = a0 + a1 + a2 + a3 + b_hh[cg];
  }
}

// ---- Phase B1: logits -> softmax over slots -> attn. grid (8, 8) ----
__global__ __launch_bounds__(256) void ph_B1(float* __restrict__ ws,
                                             float* __restrict__ att,
                                             int t, int lastit) {
  const int b = blockIdx.y;        // 0..7
  const int chunk = blockIdx.x;    // 0..7 (32 n each)
  const int wv = threadIdx.x >> 6, lane = threadIdx.x & 63;
  const float* qb = ws + OFS_Q + (size_t)b * 3 * CH;
  const float* kbuf = ws + OFS_M1;
  float* attnb = ws + OFS_ATTN;
  const float scale = 0.04419417382415922f;  // 512^-0.5
#pragma unroll
  for (int i = 0; i < 8; ++i) {
    int n = chunk * 32 + wv * 8 + i;
    const float* krow = kbuf + ((size_t)((b * CT + t) * CN + n)) * CH;
    float p0 = 0.f, p1 = 0.f, p2 = 0.f;
#pragma unroll
    for (int u = 0; u < 2; ++u) {
      int k = lane * 8 + u * 4;
      float4 kk = *(const float4*)&krow[k];
      float4 a0 = *(const float4*)&qb[k];
      float4 a1 = *(const float4*)&qb[CH + k];
      float4 a2 = *(const float4*)&qb[2 * CH + k];
      p0 += a0.x * kk.x + a0.y * kk.y + a0.z * kk.z + a0.w * kk.w;
      p1 += a1.x * kk.x + a1.y * kk.y + a1.z * kk.z + a1.w * kk.w;
      p2 += a2.x * kk.x + a2.y * kk.y + a2.z * kk.z + a2.w * kk.w;
    }
    for (int o = 32; o; o >>= 1) {
      p0 += __shfl_xor(p0, o); p1 += __shfl_xor(p1, o); p2 += __shfl_xor(p2, o);
    }
    p0 *= scale; p1 *= scale; p2 *= scale;
    float mx = fmaxf(p0, fmaxf(p1, p2));
    float e0 = expf(p0 - mx), e1 = expf(p1 - mx), e2 = expf(p2 - mx);
    float inv = 1.f / (e0 + e1 + e2);
    if (lane < 3) {
      float a = (lane == 0 ? e0 : (lane == 1 ? e1 : e2)) * inv;
      attnb[(b * 3 + lane) * CN + n] = a;
      if (lastit)
        att[((size_t)(b * CT + t) * CS + lane) * CN + n] = a;
    }
  }
}

// ---- Phase B2: U = (attn @ v) / Z. grid (2, 24) ----
__global__ __launch_bounds__(256) void ph_B2(float* __restrict__ ws, int t) {
  const int r = blockIdx.y;        // 0..23
  const int chunk = blockIdx.x;    // 0..1
  const int b = r / 3;
  const int tid = threadIdx.x;
  __shared__ float arow[CN], red[4];
  __shared__ float iz;
  const float* attnb = ws + OFS_ATTN + (size_t)r * CN;
  float a = attnb[tid];
  arow[tid] = a;
  float z = a;
  for (int o = 32; o; o >>= 1) z += __shfl_xor(z, o);
  if ((tid & 63) == 0) red[tid >> 6] = z;
  __syncthreads();
  if (tid == 0) iz = 1.f / (red[0] + red[1] + red[2] + red[3] + 1e-8f);
  __syncthreads();
  int c = chunk * 256 + tid;
  const float* v = ws + OFS_V + ((size_t)(b * CT + t) * CN) * CH + c;
  float a0 = 0.f, a1 = 0.f, a2 = 0.f, a3 = 0.f;
  for (int n = 0; n < CN; n += 4) {
    a0 += arow[n]     * v[(size_t)(n)     * CH];
    a1 += arow[n + 1] * v[(size_t)(n + 1) * CH];
    a2 += arow[n + 2] * v[(size_t)(n + 2) * CH];
    a3 += arow[n + 3] * v[(size_t)(n + 3) * CH];
  }
  ws[OFS_U + (size_t)r * CH + c] = (a0 + a1 + a2 + a3) * iz;
}

// ---- Phase C: gi = U @ w_ih.T + b_ih ; GRU combine -> h. grid (2, 24) ----
__global__ __launch_bounds__(256) void ph_C(float* __restrict__ ws,
                                            const float* __restrict__ b_ih) {
  const int r = blockIdx.y, chunk = blockIdx.x;
  const int tid = threadIdx.x;
  __shared__ float urow[CH];
  const float* U = ws + OFS_U + (size_t)r * CH;
  urow[tid] = U[tid];
  urow[tid + 256] = U[tid + 256];
  __syncthreads();
  int j = chunk * 256 + tid;
  const float* w = ws + OFS_WIHT + j;   // wihT [k][1536]
  float ar = 0.f, az = 0.f, an = 0.f;
  for (int k = 0; k < CH; ++k) {
    float u = urow[k];
    const float* wr = w + (size_t)k * CH3;
    ar += u * wr[0];
    az += u * wr[CH];
    an += u * wr[2 * CH];
  }
  ar += b_ih[j]; az += b_ih[CH + j]; an += b_ih[2 * CH + j];
  const float* gh = ws + OFS_GH + (size_t)r * CH3;
  float hr = gh[j], hz = gh[CH + j], hn = gh[2 * CH + j];
  float rr = 1.f / (1.f + expf(-(ar + hr)));
  float zz = 1.f / (1.f + expf(-(az + hz)));
  float nn = tanhf(an + rr * hn);
  float sl = ws[OFS_SLOTS + (size_t)r * CH + j];
  ws[OFS_H + (size_t)r * CH + j] = (1.f - zz) * nn + zz * sl;
}

// ---- Phase D: y = gelu(LN(h) @ w_mlp1.T + b_m1). grid (4, 24) ----
__global__ __launch_bounds__(256) void ph_D(float* __restrict__ ws,
                                            const float* __restrict__ g_lm,
                                            const float* __restrict__ b_lm,
                                            const float* __restrict__ b_m1) {
  const int r = blockIdx.y, chunk = blockIdx.x;  // chunk 0..3
  const int tid = threadIdx.x;
  const float* hrow = ws + OFS_H + (size_t)r * CH;
  __shared__ float sln[CH], red[8];
  float v0 = hrow[tid], v1 = hrow[tid + 256];
  float s = v0 + v1;
  for (int o = 32; o; o >>= 1) s += __shfl_xor(s, o);
  if ((tid & 63) == 0) red[tid >> 6] = s;
  __syncthreads();
  float mean = (red[0] + red[1] + red[2] + red[3]) * (1.f / CH);
  float d0 = v0 - mean, d1 = v1 - mean;
  float s2 = d0 * d0 + d1 * d1;
  for (int o = 32; o; o >>= 1) s2 += __shfl_xor(s2, o);
  if ((tid & 63) == 0) red[(tid >> 6) + 4] = s2;
  __syncthreads();
  float rstd = rsqrtf((red[4] + red[5] + red[6] + red[7]) * (1.f / CH) + 1e-5f);
  sln[tid]       = d0 * rstd * g_lm[tid] + b_lm[tid];
  sln[tid + 256] = d1 * rstd * g_lm[tid + 256] + b_lm[tid + 256];
  __syncthreads();
  int c = chunk * 256 + tid;               // 0..1023
  const float* w = ws + OFS_WM1T + c;      // wm1T [k][1024]
  float a0 = 0.f, a1 = 0.f, a2 = 0.f, a3 = 0.f;
  for (int k = 0; k < CH; k += 4) {
    a0 += sln[k]     * w[(size_t)(k)     * CH2];
    a1 += sln[k + 1] * w[(size_t)(k + 1) * CH2];
    a2 += sln[k + 2] * w[(size_t)(k + 2) * CH2];
    a3 += sln[k + 3] * w[(size_t)(k + 3) * CH2];
  }
  float acc = a0 + a1 + a2 + a3 + b_m1[c];
  float g = 0.5f * acc * (1.f + erff(acc * 0.70710678118654752f));
  ws[OFS_Y + (size_t)r * CH2 + c] = g;
}

// ---- Phase E: slots' = h + y @ w_mlp2.T + b_m2. grid (2, 24) ----
__global__ __launch_bounds__(256) void ph_E(float* __restrict__ ws,
                                            const float* __restrict__ b_m2,
                                            float* __restrict__ spf,
                                            int t, int lastit) {
  const int r = blockIdx.y, chunk = blockIdx.x;  // 0..1
  const int tid = threadIdx.x;
  __shared__ float yrow[CH2];
  const float* y = ws + OFS_Y + (size_t)r * CH2;
  yrow[tid] = y[tid];
  yrow[tid + 256] = y[tid + 256];
  yrow[tid + 512] = y[tid + 512];
  yrow[tid + 768] = y[tid + 768];
  __syncthreads();
  int j = chunk * 256 + tid;
  const float* w = ws + OFS_WM2T + j;      // wm2T [k=1024][512]
  float a0 = 0.f, a1 = 0.f, a2 = 0.f, a3 = 0.f;
  for (int k = 0; k < CH2; k += 4) {
    a0 += yrow[k]     * w[(size_t)(k)     * CH];
    a1 += yrow[k + 1] * w[(size_t)(k + 1) * CH];
    a2 += yrow[k + 2] * w[(size_t)(k + 2) * CH];
    a3 += yrow[k + 3] * w[(size_t)(k + 3) * CH];
  }
  float sn = ws[OFS_H + (size_t)r * CH + j] + a0 + a1 + a2 + a3 + b_m2[j];
  ws[OFS_SLOTS + (size_t)r * CH + j] = sn;
  if (lastit) {
    int b = r / 3, s5 = r % 3;
    spf[((size_t)(b * CT + t) * CS + s5) * CH + j] = sn;
  }
}

// ================= temporal attention: qkv projection =================
__global__ __launch_bounds__(256) void k_tproj(const float* __restrict__ spf,
                                               const float* __restrict__ ws_c,
                                               const float* __restrict__ b_tq,
                                               const float* __restrict__ b_tk,
                                               const float* __restrict__ b_tv,
                                               float* __restrict__ tqkv) {
  __shared__ float xr[CH];
  int row = blockIdx.x;  // bs*16 + t
  int bs = row >> 4, t = row & 15;
  int b = bs / 3, s = bs % 3;
  const float* x = spf + ((size_t)(b * CT + t) * CS + s) * CH;
  for (int i = threadIdx.x; i < CH; i += 256) xr[i] = x[i];
  __syncthreads();
  for (int p = 0; p < 6; ++p) {
    int j = p * 256 + threadIdx.x;
    const float* wT; const float* bb; int jj;
    if (j < 512)      { wT = ws_c + OFS_WTQT; bb = b_tq; jj = j; }
    else if (j < 1024){ wT = ws_c + OFS_WTKT; bb = b_tk; jj = j - 512; }
    else              { wT = ws_c + OFS_WTVT; bb = b_tv; jj = j - 1024; }
    float acc = bb[jj];
    for (int h = 0; h < CH; ++h) acc += xr[h] * wT[h * CH + jj];
    tqkv[(size_t)row * CH3 + j] = acc;
  }
}

// ================= temporal attention: per (track, head) =================
__global__ __launch_bounds__(64) void k_tattn(const float* __restrict__ tqkv,
                                              float* __restrict__ ob) {
  __shared__ float qs[16][68], ks[16][68], vs[16][68], sc[16][20];
  int bs = blockIdx.x >> 3, hh = blockIdx.x & 7;
  int lane = threadIdx.x;
  for (int i = 0; i < 16; ++i) {
    const float* base = tqkv + (size_t)(bs * 16 + i) * CH3 + hh * 64;
    qs[i][lane] = base[lane];
    ks[i][lane] = base[512 + lane];
    vs[i][lane] = base[1024 + lane];
  }
  __syncthreads();
  for (int u = 0; u < 4; ++u) {
    int ee = u * 64 + lane;
    int i = ee >> 4, j = ee & 15;
    float acc = 0.f;
    for (int d = 0; d < 64; ++d) acc += qs[i][d] * ks[j][d];
    sc[i][j] = acc * 0.125f;  // 1/sqrt(64)
  }
  __syncthreads();
  if (lane < 16) {
    float mx = -1e30f;
    for (int j = 0; j < 16; ++j) mx = fmaxf(mx, sc[lane][j]);
    float sum = 0.f;
    for (int j = 0; j < 16; ++j) { float ev = expf(sc[lane][j] - mx); sc[lane][j] = ev; sum += ev; }
    float inv = 1.f / sum;
    for (int j = 0; j < 16; ++j) sc[lane][j] *= inv;
  }
  __syncthreads();
  for (int i = 0; i < 16; ++i) {
    float acc = 0.f;
    for (int j = 0; j < 16; ++j) acc += sc[i][j] * vs[j][lane];
    ob[(size_t)(bs * 16 + i) * CH + hh * 64 + lane] = acc;
  }
}

// ================= temporal out-proj + residual + LN + mean =================
__global__ __launch_bounds__(256) void k_tout(const float* __restrict__ ob,
                                              const float* __restrict__ spf,
                                              const float* __restrict__ ws_c,
                                              const float* __restrict__ b_to,
                                              const float* __restrict__ g_lt,
                                              const float* __restrict__ b_lt,
                                              float* __restrict__ agg) {
  __shared__ float orow[CH], rrow[CH], red[8];
  int row = blockIdx.x;
  int bs = row >> 4, t = row & 15;
  int b = bs / 3, s = bs % 3;
  const float* x = spf + ((size_t)(b * CT + t) * CS + s) * CH;
  const float* o = ob + (size_t)row * CH;
  for (int i = threadIdx.x; i < CH; i += 256) orow[i] = o[i];
  __syncthreads();
  const float* wto = ws_c + OFS_WTOT;
  for (int p = 0; p < 2; ++p) {
    int j = p * 256 + threadIdx.x;
    float acc = b_to[j];
    for (int c = 0; c < CH; ++c) acc += orow[c] * wto[c * CH + j];
    rrow[j] = acc + x[j];
  }
  __syncthreads();
  float part = rrow[threadIdx.x] + rrow[threadIdx.x + 256];
  for (int o2 = 32; o2; o2 >>= 1) part += __shfl_xor(part, o2);
  if ((threadIdx.x & 63) == 0) red[threadIdx.x >> 6] = part;
  __syncthreads();
  float mean = (red[0] + red[1] + red[2] + red[3]) * (1.f / CH);
  float d0 = rrow[threadIdx.x] - mean, d1 = rrow[threadIdx.x + 256] - mean;
  float p2 = d0 * d0 + d1 * d1;
  for (int o2 = 32; o2; o2 >>= 1) p2 += __shfl_xor(p2, o2);
  __syncthreads();
  if ((threadIdx.x & 63) == 0) red[(threadIdx.x >> 6) + 4] = p2;
  __syncthreads();
  float rstd = rsqrtf((red[4] + red[5] + red[6] + red[7]) * (1.f / CH) + 1e-5f);
  for (int p = 0; p < 2; ++p) {
    int j = p * 256 + threadIdx.x;
    float xt = (rrow[j] - mean) * rstd * g_lt[j] + b_lt[j];
    atomicAdd(&agg[(size_t)bs * CH + j], xt * (1.f / CT));
  }
}

// ================= launch =================
extern "C" void kernel_launch(void* const* d_in, const int* in_sizes, int n_in,
                              void* d_out, int out_size, void* d_ws, size_t ws_size,
                              hipStream_t stream) {
  (void)in_sizes; (void)n_in; (void)out_size; (void)ws_size;
  const float* visual = (const float*)d_in[0];
  const float* noise  = (const float*)d_in[1];
  const float* mu     = (const float*)d_in[2];
  const float* sigma  = (const float*)d_in[3];
  const float* w_in   = (const float*)d_in[4];
  const float* b_in   = (const float*)d_in[5];
  const float* g_lin  = (const float*)d_in[6];
  const float* b_lin  = (const float*)d_in[7];
  const float* w_m1p  = (const float*)d_in[8];
  const float* b_m1p  = (const float*)d_in[9];
  const float* w_m2p  = (const float*)d_in[10];
  const float* b_m2p  = (const float*)d_in[11];
  const float* w_q    = (const float*)d_in[12];
  const float* w_k    = (const float*)d_in[13];
  const float* w_v    = (const float*)d_in[14];
  const float* w_ih   = (const float*)d_in[15];
  const float* w_hh   = (const float*)d_in[16];
  const float* b_ih   = (const float*)d_in[17];
  const float* b_hh   = (const float*)d_in[18];
  const float* g_ls   = (const float*)d_in[19];
  const float* b_ls   = (const float*)d_in[20];
  const float* g_lm   = (const float*)d_in[21];
  const float* b_lm   = (const float*)d_in[22];
  const float* w_mlp1 = (const float*)d_in[23];
  const float* b_mlp1 = (const float*)d_in[24];
  const float* w_mlp2 = (const float*)d_in[25];
  const float* b_mlp2 = (const float*)d_in[26];
  const float* w_tq   = (const float*)d_in[27];
  const float* b_tq   = (const float*)d_in[28];
  const float* w_tk   = (const float*)d_in[29];
  const float* b_tk   = (const float*)d_in[30];
  const float* w_tv   = (const float*)d_in[31];
  const float* b_tv   = (const float*)d_in[32];
  const float* w_to   = (const float*)d_in[33];
  const float* b_to   = (const float*)d_in[34];
  const float* g_lt   = (const float*)d_in[35];
  const float* b_lt   = (const float*)d_in[36];

  float* ws  = (float*)d_ws;
  float* out = (float*)d_out;
  float* spf = out + 12288;
  float* att = out + 12288 + 196608;

  hipLaunchKernelGGL(k_init, dim3(48), dim3(256), 0, stream, noise, mu, sigma, ws, out);
  hipLaunchKernelGGL(k_transpose, dim3(32, 48, 9), dim3(256), 0, stream,
                     w_q, w_hh, w_ih, w_mlp1, w_mlp2, w_to, w_tq, w_tk, w_tv, ws);
  // Stage 1
  hipLaunchKernelGGL(k_p1, dim3(4, 256), dim3(256), 0, stream,
                     visual, w_in, b_in, ws + OFS_P1);
  hipLaunchKernelGGL(k_rowstats, dim3(CM / 4), dim3(256), 0, stream,
                     ws + OFS_P1, ws + OFS_ST);
  hipLaunchKernelGGL(k_m1, dim3(4, 256), dim3(256), 0, stream,
                     visual, w_m1p, b_m1p, ws + OFS_M1);
  hipLaunchKernelGGL(k_feats, dim3(4, 256), dim3(256), 0, stream,
                     ws + OFS_M1, w_m2p, b_m2p, ws + OFS_ST, g_lin, b_lin, ws + OFS_P1);
  hipLaunchKernelGGL(k_kv, dim3(8, 256), dim3(256), 0, stream,
                     ws + OFS_P1, w_k, w_v, ws + OFS_M1, ws + OFS_V);
  // Stage 2: phase-split scan — launch boundaries are the barriers
  for (int t = 0; t < CT; ++t) {
    for (int it = 0; it < NITER; ++it) {
      int lastit = (it == NITER - 1) ? 1 : 0;
      hipLaunchKernelGGL(ph_A,  dim3(8, 24), dim3(256), 0, stream, ws, g_ls, b_ls, b_hh);
      hipLaunchKernelGGL(ph_B1, dim3(8, 8),  dim3(256), 0, stream, ws, att, t, lastit);
      hipLaunchKernelGGL(ph_B2, dim3(2, 24), dim3(256), 0, stream, ws, t);
      hipLaunchKernelGGL(ph_C,  dim3(2, 24), dim3(256), 0, stream, ws, b_ih);
      hipLaunchKernelGGL(ph_D,  dim3(4, 24), dim3(256), 0, stream, ws, g_lm, b_lm, b_mlp1);
      hipLaunchKernelGGL(ph_E,  dim3(2, 24), dim3(256), 0, stream, ws, b_mlp2, spf, t, lastit);
    }
  }
  // Stage 3: temporal attention
  hipLaunchKernelGGL(k_tproj, dim3(384), dim3(256), 0, stream,
                     spf, ws, b_tq, b_tk, b_tv, ws + OFS_TQKV);
  hipLaunchKernelGGL(k_tattn, dim3(192), dim3(64), 0, stream,
                     ws + OFS_TQKV, ws + OFS_TO);
  hipLaunchKernelGGL(k_tout, dim3(384), dim3(256), 0, stream,
                     ws + OFS_TO, spf, ws, b_to, g_lt, b_lt, out);
}